// Round 1
// baseline (2175.785 us; speedup 1.0000x reference)
//
#include <hip/hip_runtime.h>

#define HH 192
#define WW 192
#define PW 194
#define HWSZ (HH*WW)        // 36864
#define PHW (PW*PW)         // 37636
#define CHW (64*HWSZ)       // 2359296 per frame

typedef __attribute__((ext_vector_type(8))) short bf16x8;
typedef __attribute__((ext_vector_type(4))) short bf16x4;
typedef __attribute__((ext_vector_type(4))) float f32x4;
typedef __attribute__((ext_vector_type(4))) unsigned int u32x4;

__device__ __forceinline__ float bf2f(short h) {
    union { unsigned u; float f; } c; c.u = ((unsigned)(unsigned short)h) << 16; return c.f;
}
__device__ __forceinline__ short f2bf(float f) {
    union { float f; unsigned u; } c; c.f = f;
    unsigned u = c.u;
    return (short)((u + 0x7FFFu + ((u >> 16) & 1u)) >> 16);
}

// ---------------------------------------------------------------------------
// Implicit-GEMM 3x3 SAME conv over padded-NHWC bf16 activations.
// BM=64 couts, BN=96 pixels (half row), 2 waves. K staged in 64-cin blocks.
// wt layout: [9 taps][COUT][CIN] bf16 (cin contiguous).
// EPI: 0 = bias(+lrelu) -> bf16 store (padded or not); 2 = gate1 (p1*sig -> f32 aux);
//      3 = gate2 (p2*sig + aux -> d_out NCHW f32 + fp_state padded bf16)
// ---------------------------------------------------------------------------
template<int CIN, int COUT, int EPI>
__global__ __launch_bounds__(128)
void convk(const short* __restrict__ in0, int cs0, int cb0,
           const short* __restrict__ in1, int cs1, int cb1,
           const short* __restrict__ wt, const float* __restrict__ bias,
           short* __restrict__ outb, int pado, int rowW, int cdst, int lrelu,
           const short* __restrict__ fus, int fcb,
           float* __restrict__ taux, float* __restrict__ dml,
           short* __restrict__ fpst)
{
    constexpr int KB = CIN / 64;
    __shared__ __align__(16) short lds[3*98*64];   // 37,632 B
    const int tid = threadIdx.x;
    const int l  = tid & 63, wv = tid >> 6;
    const int lr = l & 15,  lg = l >> 4;
    int bx = blockIdx.x;
    const int nt = bx & 1; bx >>= 1;
    const int y  = bx % HH;
    const int mt = bx / HH;
    const int x0 = nt * 96;

    f32x4 acc[4][3];
#pragma unroll
    for (int a = 0; a < 4; ++a)
#pragma unroll
        for (int b = 0; b < 3; ++b) acc[a][b] = f32x4{0.f,0.f,0.f,0.f};

    // A-frag lane base: row = mt*64 + mf*16 + lr, k = lg*8
    const short* wlane = wt + (size_t)(mt*64 + lr)*CIN + lg*8;

    for (int kb = 0; kb < KB; ++kb) {
        const short* src = (kb == 0) ? in0 : in1;
        const int cs = (kb == 0) ? cs0 : cs1;
        const int cb = (kb == 0) ? cb0 : cb1;
        // ---- stage 3x98 cells x 64 cins (bf16) into LDS, slot-swizzled ----
        for (int q = tid; q < 2352; q += 128) {
            int cell = q >> 3, sub = q & 7;
            int r = cell / 98;
            int col = cell - r*98;
            const short* g = src + (size_t)((y + r)*PW + (x0 + col))*cs + cb + sub*8;
            bf16x8 v = *reinterpret_cast<const bf16x8*>(g);
            int slot = sub ^ (col & 7);
            *reinterpret_cast<bf16x8*>(&lds[(cell*8 + slot)*8]) = v;
        }
        __syncthreads();
        // ---- 9 taps x 2 k-steps of MFMA ----
#pragma unroll
        for (int dy = 0; dy < 3; ++dy) {
#pragma unroll
            for (int dx = 0; dx < 3; ++dx) {
                const short* wtap = wlane + (size_t)(dy*3 + dx)*COUT*CIN + kb*64;
#pragma unroll
                for (int ks = 0; ks < 2; ++ks) {
                    bf16x8 a0 = *reinterpret_cast<const bf16x8*>(wtap + ks*32);
                    bf16x8 a1 = *reinterpret_cast<const bf16x8*>(wtap + 16*CIN + ks*32);
                    bf16x8 a2 = *reinterpret_cast<const bf16x8*>(wtap + 32*CIN + ks*32);
                    bf16x8 a3 = *reinterpret_cast<const bf16x8*>(wtap + 48*CIN + ks*32);
#pragma unroll
                    for (int nf = 0; nf < 3; ++nf) {
                        int colc = wv*48 + nf*16 + lr + dx;
                        int slot = (ks*4 + lg) ^ (colc & 7);
                        bf16x8 bv = *reinterpret_cast<const bf16x8*>(&lds[((dy*98 + colc)*8 + slot)*8]);
                        acc[0][nf] = __builtin_amdgcn_mfma_f32_16x16x32_bf16(a0, bv, acc[0][nf], 0,0,0);
                        acc[1][nf] = __builtin_amdgcn_mfma_f32_16x16x32_bf16(a1, bv, acc[1][nf], 0,0,0);
                        acc[2][nf] = __builtin_amdgcn_mfma_f32_16x16x32_bf16(a2, bv, acc[2][nf], 0,0,0);
                        acc[3][nf] = __builtin_amdgcn_mfma_f32_16x16x32_bf16(a3, bv, acc[3][nf], 0,0,0);
                    }
                }
            }
        }
        if (kb + 1 < KB) __syncthreads();
    }

    // ---- epilogue: D row = lg*4 + j (+mf*16+mt*64), col = lr ----
#pragma unroll
    for (int mf = 0; mf < 4; ++mf) {
        const int coutb = mt*64 + mf*16 + lg*4;
        f32x4 bv = *reinterpret_cast<const f32x4*>(bias + coutb);
#pragma unroll
        for (int nf = 0; nf < 3; ++nf) {
            const int x = x0 + wv*48 + nf*16 + lr;
            f32x4 v = acc[mf][nf];
            if constexpr (EPI == 0) {
                bf16x4 pk;
#pragma unroll
                for (int j = 0; j < 4; ++j) {
                    float t = v[j] + bv[j];
                    if (lrelu) t = (t >= 0.f) ? t : 0.1f*t;
                    pk[j] = f2bf(t);
                }
                *reinterpret_cast<bf16x4*>(outb + (size_t)((y+pado)*rowW + (x+pado))*cdst + coutb) = pk;
            } else if constexpr (EPI == 2) {
                bf16x4 pv = *reinterpret_cast<const bf16x4*>(fus + (size_t)((y+1)*PW + (x+1))*128 + fcb + coutb);
                f32x4 o;
#pragma unroll
                for (int j = 0; j < 4; ++j) {
                    float g = 1.f / (1.f + __expf(-(v[j] + bv[j])));
                    o[j] = bf2f(pv[j]) * g;
                }
                *reinterpret_cast<f32x4*>(taux + (size_t)(y*WW + x)*64 + coutb) = o;
            } else {  // EPI == 3
                bf16x4 pv = *reinterpret_cast<const bf16x4*>(fus + (size_t)((y+1)*PW + (x+1))*128 + fcb + coutb);
                f32x4 tv = *reinterpret_cast<const f32x4*>(taux + (size_t)(y*WW + x)*64 + coutb);
                bf16x4 pk;
#pragma unroll
                for (int j = 0; j < 4; ++j) {
                    float g = 1.f / (1.f + __expf(-(v[j] + bv[j])));
                    float r = bf2f(pv[j]) * g + tv[j];
                    dml[(size_t)(coutb + j)*HWSZ + y*WW + x] = r;
                    pk[j] = f2bf(r);
                }
                *reinterpret_cast<bf16x4*>(fpst + (size_t)((y+1)*PW + (x+1))*64 + coutb) = pk;
            }
        }
    }
}

// ---------------------------------------------------------------------------
// Dynamic per-pixel 3x3 kernel conv: out[c,y,x] = sum_t kp[y,x,t*64+c] * fp[y+dy,x+dx,c]
// kp: unpadded NHWC [HW][576] bf16; fp, out: padded NHWC [PHW][64] bf16
// ---------------------------------------------------------------------------
__global__ __launch_bounds__(256)
void kconvk(const short* __restrict__ kp, const short* __restrict__ fp,
            short* __restrict__ outp)
{
    int t  = blockIdx.x*256 + threadIdx.x;
    int cg = t & 7, pix = t >> 3;
    int y = pix / WW, x = pix - y*WW;
    float acc[8];
#pragma unroll
    for (int e = 0; e < 8; ++e) acc[e] = 0.f;
    const short* kpp = kp + (size_t)pix*576 + cg*8;
#pragma unroll
    for (int tap = 0; tap < 9; ++tap) {
        int dy = tap / 3, dx = tap - dy*3;
        bf16x8 kv = *reinterpret_cast<const bf16x8*>(kpp + tap*64);
        bf16x8 fv = *reinterpret_cast<const bf16x8*>(fp + (size_t)((y+dy)*PW + (x+dx))*64 + cg*8);
#pragma unroll
        for (int e = 0; e < 8; ++e) acc[e] += bf2f(kv[e]) * bf2f(fv[e]);
    }
    bf16x8 o;
#pragma unroll
    for (int e = 0; e < 8; ++e) o[e] = f2bf(acc[e]);
    *reinterpret_cast<bf16x8*>(outp + (size_t)((y+1)*PW + (x+1))*64 + cg*8) = o;
}

// ---------------------------------------------------------------------------
// NCHW f32 frame -> padded NHWC bf16 (interior only; border pre-zeroed)
// ---------------------------------------------------------------------------
__global__ __launch_bounds__(64)
void tonhwck(const float* __restrict__ src, short* __restrict__ dst)
{
    int b = blockIdx.x;
    int y = b / 3, x = (b - y*3)*64 + threadIdx.x;
    unsigned pk[32];
#pragma unroll
    for (int c = 0; c < 64; ++c) {
        unsigned h = (unsigned)(unsigned short)f2bf(src[(size_t)c*HWSZ + y*WW + x]);
        if (c & 1) pk[c>>1] |= h << 16; else pk[c>>1] = h;
    }
    u32x4* d = reinterpret_cast<u32x4*>(dst + (size_t)((y+1)*PW + (x+1))*64);
#pragma unroll
    for (int q = 0; q < 8; ++q) d[q] = u32x4{pk[4*q], pk[4*q+1], pk[4*q+2], pk[4*q+3]};
}

// ---------------------------------------------------------------------------
// weight [COUT][CIN][3][3] f32 -> [9][COUT][CIN] bf16
// ---------------------------------------------------------------------------
__global__ void wtxk(const float* __restrict__ src, short* __restrict__ dst,
                     int cout_n, int cin_n)
{
    int i = blockIdx.x*256 + threadIdx.x;
    if (i >= cout_n*cin_n) return;
    int co = i / cin_n, ci = i - co*cin_n;
    const float* s = src + (size_t)i*9;
#pragma unroll
    for (int t = 0; t < 9; ++t)
        dst[((size_t)t*cout_n + co)*cin_n + ci] = f2bf(s[t]);
}

extern "C" void kernel_launch(void* const* d_in, const int* in_sizes, int n_in,
                              void* d_out, int out_size, void* d_ws, size_t ws_size,
                              hipStream_t stream)
{
    const float* feature = (const float*)d_in[0];
    const float* w_kc1 = (const float*)d_in[1];
    const float* b_kc1 = (const float*)d_in[2];
    const float* w_kc2 = (const float*)d_in[3];
    const float* b_kc2 = (const float*)d_in[4];
    const float* w_c1  = (const float*)d_in[5];
    const float* b_c1  = (const float*)d_in[6];
    const float* w_c2  = (const float*)d_in[7];
    const float* b_c2  = (const float*)d_in[8];
    const float* w_c3  = (const float*)d_in[9];
    const float* b_c3  = (const float*)d_in[10];
    float* out = (float*)d_out;
    char* ws = (char*)d_ws;

    size_t off = 0;
    auto alloc = [&](size_t bytes) -> void* {
        void* p = ws + off; off += (bytes + 255) & ~(size_t)255; return p;
    };
    short* wt1   = (short*)alloc((size_t)9*64*128*2);
    short* wt2   = (short*)alloc((size_t)9*576*64*2);
    short* wtc1  = (short*)alloc((size_t)9*128*128*2);
    short* wtc2  = (short*)alloc((size_t)9*64*64*2);
    short* wtc3  = (short*)alloc((size_t)9*64*64*2);
    char*  zbase = ws + off;                  // contiguous zero-init block
    short* featX   = (short*)alloc((size_t)PHW*64*2);
    short* fpinit  = (short*)alloc((size_t)PHW*64*2);
    short* fpstate = (short*)alloc((size_t)PHW*64*2);
    short* t1      = (short*)alloc((size_t)PHW*64*2);
    short* fpmid   = (short*)alloc((size_t)PHW*64*2);
    short* fusion  = (short*)alloc((size_t)PHW*128*2);
    size_t zbytes = (size_t)((ws + off) - zbase);
    short* kp   = (short*)alloc((size_t)HWSZ*576*2);
    float* tmp4 = (float*)alloc((size_t)HWSZ*64*4);
    (void)ws_size; (void)in_sizes; (void)n_in; (void)out_size;

    hipMemsetAsync(zbase, 0, zbytes, stream);   // borders of padded buffers = 0
    wtxk<<<(64*128 + 255)/256, 256, 0, stream>>>(w_kc1, wt1, 64, 128);
    wtxk<<<(576*64 + 255)/256, 256, 0, stream>>>(w_kc2, wt2, 576, 64);
    wtxk<<<(128*128 + 255)/256, 256, 0, stream>>>(w_c1, wtc1, 128, 128);
    wtxk<<<(64*64 + 255)/256, 256, 0, stream>>>(w_c2, wtc2, 64, 64);
    wtxk<<<(64*64 + 255)/256, 256, 0, stream>>>(w_c3, wtc3, 64, 64);
    tonhwck<<<576, 64, 0, stream>>>(feature + (size_t)9*CHW, fpinit);

    for (int i = 8; i >= 0; --i) {
        const short* fpin = (i == 8) ? fpinit : fpstate;
        tonhwck<<<576, 64, 0, stream>>>(feature + (size_t)i*CHW, featX);
        // t1 = lrelu(conv(concat(x, fp), w_kc1) + b)
        convk<128, 64, 0><<<384, 128, 0, stream>>>(featX, 64, 0, fpin, 64, 0,
            wt1, b_kc1, t1, 1, PW, 64, 1, nullptr, 0, nullptr, nullptr, nullptr);
        // kp = conv(t1, w_kc2) + b
        convk<64, 576, 0><<<3456, 128, 0, stream>>>(t1, 64, 0, nullptr, 0, 0,
            wt2, b_kc2, kp, 0, WW, 576, 0, nullptr, 0, nullptr, nullptr, nullptr);
        // fpmid = kernel_conv(fp, kp)
        kconvk<<<1152, 256, 0, stream>>>(kp, fpin, fpmid);
        // fusion = lrelu(conv(concat(x, fpmid), w_c1) + b)
        convk<128, 128, 0><<<768, 128, 0, stream>>>(featX, 64, 0, fpmid, 64, 0,
            wtc1, b_c1, fusion, 1, PW, 128, 1, nullptr, 0, nullptr, nullptr, nullptr);
        // tmp4 = p1 * sigmoid(conv(p1, w_c2) + b)
        convk<64, 64, 2><<<384, 128, 0, stream>>>(fusion, 128, 0, nullptr, 0, 0,
            wtc2, b_c2, nullptr, 0, 0, 0, 0, fusion, 0, tmp4, nullptr, nullptr);
        // out[:,i] = fpstate = p2 * sigmoid(conv(p2, w_c3) + b) + tmp4
        convk<64, 64, 3><<<384, 128, 0, stream>>>(fusion, 128, 64, nullptr, 0, 0,
            wtc3, b_c3, nullptr, 0, 0, 0, 0, fusion, 64, tmp4,
            out + (size_t)i*CHW, fpstate);
    }
    hipMemcpyAsync(out + (size_t)9*CHW, feature + (size_t)9*CHW,
                   (size_t)CHW*sizeof(float), hipMemcpyDeviceToDevice, stream);
}